// Round 1
// baseline (1370.451 us; speedup 1.0000x reference)
//
#include <hip/hip_runtime.h>
#include <math.h>

#define N_NODES 20000
#define N_EDGES 640000
#define HID 128

// ---------- degree / normalization ----------
__global__ __launch_bounds__(256) void k_deg_init(float* deg) {
    int i = blockIdx.x * 256 + threadIdx.x;
    if (i < N_NODES) deg[i] = 1.0f;   // self-loop weight
}

__global__ __launch_bounds__(256) void k_deg_edges(float* deg, const int* __restrict__ dst,
                                                   const float* __restrict__ ew) {
    int e = blockIdx.x * 256 + threadIdx.x;
    if (e < N_EDGES) atomicAdd(&deg[dst[e]], ew[e]);
}

__global__ __launch_bounds__(256) void k_dinv(float* dinv) {
    int i = blockIdx.x * 256 + threadIdx.x;
    if (i < N_NODES) {
        float d = dinv[i];
        dinv[i] = d > 0.f ? rsqrtf(d) : 0.f;
    }
}

// ---------- GEMM [N,128] @ [128,128], epilogue writes xw and agg := xw * dinv^2 ----------
__global__ __launch_bounds__(256) void k_gemm_self(const float* __restrict__ A,
                                                   const float* __restrict__ W,
                                                   const float* __restrict__ dinv,
                                                   float* __restrict__ out,
                                                   float* __restrict__ agg) {
    __shared__ float as[8 * HID];
    int r0 = blockIdx.x * 8;
    int tid = threadIdx.x;
    // load 8 contiguous rows (1024 floats) with float4
    ((float4*)as)[tid] = ((const float4*)(A + (size_t)r0 * HID))[tid];
    __syncthreads();
    int c = tid & 127, half = tid >> 7;   // rows half, half+2, half+4, half+6
    float acc0 = 0, acc1 = 0, acc2 = 0, acc3 = 0;
#pragma unroll 4
    for (int k = 0; k < 128; k++) {
        float w = W[k * HID + c];
        acc0 += as[(half + 0) * HID + k] * w;
        acc1 += as[(half + 2) * HID + k] * w;
        acc2 += as[(half + 4) * HID + k] * w;
        acc3 += as[(half + 6) * HID + k] * w;
    }
    int r; float dv;
    r = r0 + half;     dv = dinv[r]; out[(size_t)r * HID + c] = acc0; agg[(size_t)r * HID + c] = acc0 * dv * dv;
    r = r0 + half + 2; dv = dinv[r]; out[(size_t)r * HID + c] = acc1; agg[(size_t)r * HID + c] = acc1 * dv * dv;
    r = r0 + half + 4; dv = dinv[r]; out[(size_t)r * HID + c] = acc2; agg[(size_t)r * HID + c] = acc2 * dv * dv;
    r = r0 + half + 6; dv = dinv[r]; out[(size_t)r * HID + c] = acc3; agg[(size_t)r * HID + c] = acc3 * dv * dv;
}

// ---------- edge scatter: agg[dst] += xw[src] * norm, one wave per edge ----------
__global__ __launch_bounds__(256) void k_scatter(const float* __restrict__ xw,
                                                 float* __restrict__ agg,
                                                 const int* __restrict__ src,
                                                 const int* __restrict__ dst,
                                                 const float* __restrict__ ew,
                                                 const float* __restrict__ dinv) {
    int e = blockIdx.x * 4 + (threadIdx.x >> 6);
    int lane = threadIdx.x & 63;
    int s = src[e], d = dst[e];
    float nrm = dinv[s] * ew[e] * dinv[d];
    float2 v = ((const float2*)(xw + (size_t)s * HID))[lane];
    float* ap = agg + (size_t)d * HID + lane * 2;
    atomicAdd(ap,     v.x * nrm);
    atomicAdd(ap + 1, v.y * nrm);
}

// ---------- elementwise ----------
__global__ __launch_bounds__(256) void k_bias_relu(float* a, const float* __restrict__ b) {
    int i = blockIdx.x * 256 + threadIdx.x;
    float v = a[i] + b[i & 127];
    a[i] = v > 0.f ? v : 0.f;
}

__global__ __launch_bounds__(256) void k_sigmoid(float* a, const float* __restrict__ b) {
    int i = blockIdx.x * 256 + threadIdx.x;
    float v = a[i] + b[i & 127];
    a[i] = 1.f / (1.f + __expf(-v));
}

// ---------- gating GEMMs: u,r = sigmoid([xg,h] @ W{u,r} + b) ----------
__global__ __launch_bounds__(256) void k_gate_ur(const float* __restrict__ xg, const float* __restrict__ h,
                                                 const float* __restrict__ Wu, const float* __restrict__ bu,
                                                 const float* __restrict__ Wr, const float* __restrict__ br,
                                                 float* __restrict__ u, float* __restrict__ r) {
    __shared__ float xh[4 * 256];
    int r0 = blockIdx.x * 4;
    int tid = threadIdx.x;
    {
        int row = tid >> 6;     // 0..3
        int seg = tid & 63;     // float4 slot within a 256-float row
        float4 v;
        if (seg < 32) v = ((const float4*)(xg + (size_t)(r0 + row) * HID))[seg];
        else          v = ((const float4*)(h  + (size_t)(r0 + row) * HID))[seg - 32];
        ((float4*)xh)[tid] = v;
    }
    __syncthreads();
    int c = tid & 127, half = tid >> 7;   // rows half, half+2
    float au0 = 0, ar0 = 0, au1 = 0, ar1 = 0;
#pragma unroll 4
    for (int k = 0; k < 256; k++) {
        float wu = Wu[k * HID + c];
        float wr = Wr[k * HID + c];
        float x0 = xh[(half + 0) * 256 + k];
        float x1 = xh[(half + 2) * 256 + k];
        au0 += x0 * wu; ar0 += x0 * wr;
        au1 += x1 * wu; ar1 += x1 * wr;
    }
    int rw;
    rw = r0 + half;
    u[(size_t)rw * HID + c] = 1.f / (1.f + __expf(-(au0 + bu[c])));
    r[(size_t)rw * HID + c] = 1.f / (1.f + __expf(-(ar0 + br[c])));
    rw = r0 + half + 2;
    u[(size_t)rw * HID + c] = 1.f / (1.f + __expf(-(au1 + bu[c])));
    r[(size_t)rw * HID + c] = 1.f / (1.f + __expf(-(ar1 + br[c])));
}

// ---------- c gate + final blend: out = u*h + (1-u)*tanh([xg, r*h] @ Wc + bc) ----------
__global__ __launch_bounds__(256) void k_gate_c(const float* __restrict__ xg, const float* __restrict__ h,
                                                const float* __restrict__ r, const float* __restrict__ u,
                                                const float* __restrict__ Wc, const float* __restrict__ bc,
                                                float* __restrict__ out) {
    __shared__ float xh[4 * 256];
    int r0 = blockIdx.x * 4;
    int tid = threadIdx.x;
    {
        int row = tid >> 6;
        int seg = tid & 63;
        float4 v;
        if (seg < 32) v = ((const float4*)(xg + (size_t)(r0 + row) * HID))[seg];
        else {
            float4 hv = ((const float4*)(h + (size_t)(r0 + row) * HID))[seg - 32];
            float4 rv = ((const float4*)(r + (size_t)(r0 + row) * HID))[seg - 32];
            v = make_float4(hv.x * rv.x, hv.y * rv.y, hv.z * rv.z, hv.w * rv.w);
        }
        ((float4*)xh)[tid] = v;
    }
    __syncthreads();
    int c = tid & 127, half = tid >> 7;
    float a0 = 0, a1 = 0;
#pragma unroll 4
    for (int k = 0; k < 256; k++) {
        float wc = Wc[k * HID + c];
        a0 += xh[(half + 0) * 256 + k] * wc;
        a1 += xh[(half + 2) * 256 + k] * wc;
    }
    int rw;
    rw = r0 + half;
    {
        float cv = tanhf(a0 + bc[c]);
        float uv = u[(size_t)rw * HID + c];
        float hv = h[(size_t)rw * HID + c];
        out[(size_t)rw * HID + c] = uv * hv + (1.f - uv) * cv;
    }
    rw = r0 + half + 2;
    {
        float cv = tanhf(a1 + bc[c]);
        float uv = u[(size_t)rw * HID + c];
        float hv = h[(size_t)rw * HID + c];
        out[(size_t)rw * HID + c] = uv * hv + (1.f - uv) * cv;
    }
}

extern "C" void kernel_launch(void* const* d_in, const int* in_sizes, int n_in,
                              void* d_out, int out_size, void* d_ws, size_t ws_size,
                              hipStream_t stream) {
    const float* x  = (const float*)d_in[0];
    const int*   ei = (const int*)d_in[1];
    const float* ew = (const float*)d_in[2];
    const float* h  = (const float*)d_in[3];
    const float* W1 = (const float*)d_in[4];
    const float* b1 = (const float*)d_in[5];
    const float* W2 = (const float*)d_in[6];
    const float* b2 = (const float*)d_in[7];
    const float* Wu = (const float*)d_in[8];
    const float* bu = (const float*)d_in[9];
    const float* Wr = (const float*)d_in[10];
    const float* br = (const float*)d_in[11];
    const float* Wc = (const float*)d_in[12];
    const float* bc = (const float*)d_in[13];
    const int* src = ei;
    const int* dst = ei + N_EDGES;
    float* out = (float*)d_out;

    const size_t NH = (size_t)N_NODES * HID;
    float* ws   = (float*)d_ws;
    float* dinv = ws;                 // N (padded to 20224 for 16B alignment of next buf)
    float* xw   = ws + 20224;         // N*H
    float* agg1 = xw + NH;            // N*H (becomes h1)
    float* hw2  = agg1 + NH;          // N*H
    float* agg2 = hw2 + NH;           // N*H (becomes xg)
    float* uu   = agg2 + NH;          // N*H
    float* rr   = uu + NH;            // N*H

    k_deg_init<<<(N_NODES + 255) / 256, 256, 0, stream>>>(dinv);
    k_deg_edges<<<N_EDGES / 256, 256, 0, stream>>>(dinv, dst, ew);
    k_dinv<<<(N_NODES + 255) / 256, 256, 0, stream>>>(dinv);

    // layer 1: xw = x@W1 ; agg1 = selfloop-init ; scatter ; h1 = relu(agg1+b1)
    k_gemm_self<<<N_NODES / 8, 256, 0, stream>>>(x, W1, dinv, xw, agg1);
    k_scatter<<<N_EDGES / 4, 256, 0, stream>>>(xw, agg1, src, dst, ew, dinv);
    k_bias_relu<<<(int)(NH / 256), 256, 0, stream>>>(agg1, b1);

    // layer 2: hw2 = h1@W2 ; agg2 = selfloop-init ; scatter ; xg = sigmoid(agg2+b2)
    k_gemm_self<<<N_NODES / 8, 256, 0, stream>>>(agg1, W2, dinv, hw2, agg2);
    k_scatter<<<N_EDGES / 4, 256, 0, stream>>>(hw2, agg2, src, dst, ew, dinv);
    k_sigmoid<<<(int)(NH / 256), 256, 0, stream>>>(agg2, b2);

    // gating
    k_gate_ur<<<N_NODES / 4, 256, 0, stream>>>(agg2, h, Wu, bu, Wr, br, uu, rr);
    k_gate_c<<<N_NODES / 4, 256, 0, stream>>>(agg2, h, rr, uu, Wc, bc, out);
}

// Round 2
// 512.686 us; speedup vs baseline: 2.6731x; 2.6731x over previous
//
#include <hip/hip_runtime.h>
#include <math.h>

#define N_NODES 20000
#define N_EDGES 640000
#define HID 128
#define NPAD 20224   // N_NODES padded for 16B-aligned workspace carving

// ---------- init: self-loop degree + zero histogram ----------
__global__ __launch_bounds__(256) void k_init(float* deg, int* cnt) {
    int i = blockIdx.x * 256 + threadIdx.x;
    if (i < N_NODES) { deg[i] = 1.0f; cnt[i] = 0; }
}

// ---------- per-edge: weighted degree + in-degree histogram ----------
__global__ __launch_bounds__(256) void k_deg_hist(float* deg, int* cnt,
                                                  const int* __restrict__ dst,
                                                  const float* __restrict__ ew) {
    int e = blockIdx.x * 256 + threadIdx.x;
    if (e < N_EDGES) {
        int d = dst[e];
        atomicAdd(&deg[d], ew[e]);
        atomicAdd(&cnt[d], 1);
    }
}

__global__ __launch_bounds__(256) void k_dinv(float* dinv) {
    int i = blockIdx.x * 256 + threadIdx.x;
    if (i < N_NODES) {
        float d = dinv[i];
        dinv[i] = d > 0.f ? rsqrtf(d) : 0.f;
    }
}

// ---------- single-block exclusive scan of cnt -> row_ptr (+ cursor copy) ----------
__global__ __launch_bounds__(1024) void k_scan(const int* __restrict__ cnt,
                                               int* __restrict__ rp,
                                               int* __restrict__ cur) {
    __shared__ int smem[1024];
    __shared__ int carry;
    if (threadIdx.x == 0) carry = 0;
    __syncthreads();
    for (int base = 0; base < N_NODES; base += 1024) {
        int i = base + threadIdx.x;
        int v = (i < N_NODES) ? cnt[i] : 0;
        smem[threadIdx.x] = v;
        __syncthreads();
        for (int off = 1; off < 1024; off <<= 1) {
            int t = (threadIdx.x >= off) ? smem[threadIdx.x - off] : 0;
            __syncthreads();
            smem[threadIdx.x] += t;
            __syncthreads();
        }
        int excl = smem[threadIdx.x] - v + carry;
        if (i < N_NODES) { rp[i] = excl; cur[i] = excl; }
        __syncthreads();
        if (threadIdx.x == 1023) carry += smem[1023];
        __syncthreads();
    }
    if (threadIdx.x == 0) rp[N_NODES] = carry;   // == N_EDGES
}

// ---------- CSR fill: slot per edge, store src idx + precomputed norm ----------
__global__ __launch_bounds__(256) void k_fill(const int* __restrict__ src,
                                              const int* __restrict__ dst,
                                              const float* __restrict__ ew,
                                              const float* __restrict__ dinv,
                                              int* cur,
                                              int* __restrict__ csr_src,
                                              float* __restrict__ csr_w) {
    int e = blockIdx.x * 256 + threadIdx.x;
    if (e < N_EDGES) {
        int s = src[e], d = dst[e];
        int slot = atomicAdd(&cur[d], 1);
        csr_src[slot] = s;
        csr_w[slot] = dinv[s] * ew[e] * dinv[d];
    }
}

// ---------- GEMM [N,128] @ [128,128] -> xw ----------
__global__ __launch_bounds__(256) void k_gemm(const float* __restrict__ A,
                                              const float* __restrict__ W,
                                              float* __restrict__ out) {
    __shared__ float as[8 * HID];
    int r0 = blockIdx.x * 8;
    int tid = threadIdx.x;
    ((float4*)as)[tid] = ((const float4*)(A + (size_t)r0 * HID))[tid];
    __syncthreads();
    int c = tid & 127, half = tid >> 7;
    float acc0 = 0, acc1 = 0, acc2 = 0, acc3 = 0;
#pragma unroll 4
    for (int k = 0; k < 128; k++) {
        float w = W[k * HID + c];
        acc0 += as[(half + 0) * HID + k] * w;
        acc1 += as[(half + 2) * HID + k] * w;
        acc2 += as[(half + 4) * HID + k] * w;
        acc3 += as[(half + 6) * HID + k] * w;
    }
    out[(size_t)(r0 + half + 0) * HID + c] = acc0;
    out[(size_t)(r0 + half + 2) * HID + c] = acc1;
    out[(size_t)(r0 + half + 4) * HID + c] = acc2;
    out[(size_t)(r0 + half + 6) * HID + c] = acc3;
}

// ---------- gather aggregation: one wave per dst node ----------
// acc = xw[node]*dinv^2 (self loop) + sum_j xw[csr_src[j]] * csr_w[j]; then bias+act
__global__ __launch_bounds__(256) void k_aggregate(const float* __restrict__ xw,
                                                   float* __restrict__ outbuf,
                                                   const int* __restrict__ rp,
                                                   const int* __restrict__ csr_src,
                                                   const float* __restrict__ csr_w,
                                                   const float* __restrict__ dinv,
                                                   const float* __restrict__ bias,
                                                   int act) {
    int node = blockIdx.x * 4 + (threadIdx.x >> 6);
    int lane = threadIdx.x & 63;
    float dv = dinv[node];
    float2 acc = ((const float2*)(xw + (size_t)node * HID))[lane];
    acc.x *= dv * dv; acc.y *= dv * dv;
    int j = rp[node], end = rp[node + 1];
    for (; j + 3 < end; j += 4) {
        int s0 = csr_src[j], s1 = csr_src[j + 1], s2 = csr_src[j + 2], s3 = csr_src[j + 3];
        float w0 = csr_w[j], w1 = csr_w[j + 1], w2 = csr_w[j + 2], w3 = csr_w[j + 3];
        float2 v0 = ((const float2*)(xw + (size_t)s0 * HID))[lane];
        float2 v1 = ((const float2*)(xw + (size_t)s1 * HID))[lane];
        float2 v2 = ((const float2*)(xw + (size_t)s2 * HID))[lane];
        float2 v3 = ((const float2*)(xw + (size_t)s3 * HID))[lane];
        acc.x += v0.x * w0; acc.y += v0.y * w0;
        acc.x += v1.x * w1; acc.y += v1.y * w1;
        acc.x += v2.x * w2; acc.y += v2.y * w2;
        acc.x += v3.x * w3; acc.y += v3.y * w3;
    }
    for (; j < end; j++) {
        int s = csr_src[j];
        float w = csr_w[j];
        float2 v = ((const float2*)(xw + (size_t)s * HID))[lane];
        acc.x += v.x * w; acc.y += v.y * w;
    }
    float2 b = ((const float2*)bias)[lane];
    acc.x += b.x; acc.y += b.y;
    if (act == 0) {
        acc.x = fmaxf(acc.x, 0.f); acc.y = fmaxf(acc.y, 0.f);
    } else {
        acc.x = 1.f / (1.f + __expf(-acc.x)); acc.y = 1.f / (1.f + __expf(-acc.y));
    }
    ((float2*)(outbuf + (size_t)node * HID))[lane] = acc;
}

// ---------- gating GEMMs: u,r = sigmoid([xg,h] @ W{u,r} + b) ----------
__global__ __launch_bounds__(256) void k_gate_ur(const float* __restrict__ xg, const float* __restrict__ h,
                                                 const float* __restrict__ Wu, const float* __restrict__ bu,
                                                 const float* __restrict__ Wr, const float* __restrict__ br,
                                                 float* __restrict__ u, float* __restrict__ r) {
    __shared__ float xh[4 * 256];
    int r0 = blockIdx.x * 4;
    int tid = threadIdx.x;
    {
        int row = tid >> 6;
        int seg = tid & 63;
        float4 v;
        if (seg < 32) v = ((const float4*)(xg + (size_t)(r0 + row) * HID))[seg];
        else          v = ((const float4*)(h  + (size_t)(r0 + row) * HID))[seg - 32];
        ((float4*)xh)[tid] = v;
    }
    __syncthreads();
    int c = tid & 127, half = tid >> 7;
    float au0 = 0, ar0 = 0, au1 = 0, ar1 = 0;
#pragma unroll 4
    for (int k = 0; k < 256; k++) {
        float wu = Wu[k * HID + c];
        float wr = Wr[k * HID + c];
        float x0 = xh[(half + 0) * 256 + k];
        float x1 = xh[(half + 2) * 256 + k];
        au0 += x0 * wu; ar0 += x0 * wr;
        au1 += x1 * wu; ar1 += x1 * wr;
    }
    int rw;
    rw = r0 + half;
    u[(size_t)rw * HID + c] = 1.f / (1.f + __expf(-(au0 + bu[c])));
    r[(size_t)rw * HID + c] = 1.f / (1.f + __expf(-(ar0 + br[c])));
    rw = r0 + half + 2;
    u[(size_t)rw * HID + c] = 1.f / (1.f + __expf(-(au1 + bu[c])));
    r[(size_t)rw * HID + c] = 1.f / (1.f + __expf(-(ar1 + br[c])));
}

// ---------- c gate + final blend ----------
__global__ __launch_bounds__(256) void k_gate_c(const float* __restrict__ xg, const float* __restrict__ h,
                                                const float* __restrict__ r, const float* __restrict__ u,
                                                const float* __restrict__ Wc, const float* __restrict__ bc,
                                                float* __restrict__ out) {
    __shared__ float xh[4 * 256];
    int r0 = blockIdx.x * 4;
    int tid = threadIdx.x;
    {
        int row = tid >> 6;
        int seg = tid & 63;
        float4 v;
        if (seg < 32) v = ((const float4*)(xg + (size_t)(r0 + row) * HID))[seg];
        else {
            float4 hv = ((const float4*)(h + (size_t)(r0 + row) * HID))[seg - 32];
            float4 rv = ((const float4*)(r + (size_t)(r0 + row) * HID))[seg - 32];
            v = make_float4(hv.x * rv.x, hv.y * rv.y, hv.z * rv.z, hv.w * rv.w);
        }
        ((float4*)xh)[tid] = v;
    }
    __syncthreads();
    int c = tid & 127, half = tid >> 7;
    float a0 = 0, a1 = 0;
#pragma unroll 4
    for (int k = 0; k < 256; k++) {
        float wc = Wc[k * HID + c];
        a0 += xh[(half + 0) * 256 + k] * wc;
        a1 += xh[(half + 2) * 256 + k] * wc;
    }
    int rw;
    rw = r0 + half;
    {
        float cv = tanhf(a0 + bc[c]);
        float uv = u[(size_t)rw * HID + c];
        float hv = h[(size_t)rw * HID + c];
        out[(size_t)rw * HID + c] = uv * hv + (1.f - uv) * cv;
    }
    rw = r0 + half + 2;
    {
        float cv = tanhf(a1 + bc[c]);
        float uv = u[(size_t)rw * HID + c];
        float hv = h[(size_t)rw * HID + c];
        out[(size_t)rw * HID + c] = uv * hv + (1.f - uv) * cv;
    }
}

extern "C" void kernel_launch(void* const* d_in, const int* in_sizes, int n_in,
                              void* d_out, int out_size, void* d_ws, size_t ws_size,
                              hipStream_t stream) {
    const float* x  = (const float*)d_in[0];
    const int*   ei = (const int*)d_in[1];
    const float* ew = (const float*)d_in[2];
    const float* h  = (const float*)d_in[3];
    const float* W1 = (const float*)d_in[4];
    const float* b1 = (const float*)d_in[5];
    const float* W2 = (const float*)d_in[6];
    const float* b2 = (const float*)d_in[7];
    const float* Wu = (const float*)d_in[8];
    const float* bu = (const float*)d_in[9];
    const float* Wr = (const float*)d_in[10];
    const float* br = (const float*)d_in[11];
    const float* Wc = (const float*)d_in[12];
    const float* bc = (const float*)d_in[13];
    const int* src = ei;
    const int* dst = ei + N_EDGES;
    float* out = (float*)d_out;

    const size_t NH = (size_t)N_NODES * HID;
    // workspace carve (all 16B-aligned chunks); total ~56.6 MB
    float* ws      = (float*)d_ws;
    float* dinv    = ws;                         // NPAD
    int*   rp      = (int*)(ws + NPAD);          // NPAD (uses N_NODES+1)
    int*   cnt     = (int*)(ws + 2 * NPAD);      // NPAD
    int*   cur     = (int*)(ws + 3 * NPAD);      // NPAD
    int*   csr_src = (int*)(ws + 4 * NPAD);      // N_EDGES
    float* csr_w   = ws + 4 * NPAD + N_EDGES;    // N_EDGES
    float* big     = ws + 4 * NPAD + 2 * N_EDGES;
    float* xw  = big;            // NH, reused for both layers
    float* h1  = big + NH;       // NH
    float* xg  = big + 2 * NH;   // NH
    float* uu  = big + 3 * NH;   // NH
    float* rr  = big + 4 * NH;   // NH

    // normalization + CSR build (once, reused by both layers)
    k_init<<<(N_NODES + 255) / 256, 256, 0, stream>>>(dinv, cnt);
    k_deg_hist<<<N_EDGES / 256, 256, 0, stream>>>(dinv, cnt, dst, ew);
    k_dinv<<<(N_NODES + 255) / 256, 256, 0, stream>>>(dinv);
    k_scan<<<1, 1024, 0, stream>>>(cnt, rp, cur);
    k_fill<<<N_EDGES / 256, 256, 0, stream>>>(src, dst, ew, dinv, cur, csr_src, csr_w);

    // layer 1: xw = x@W1 ; h1 = relu(agg + b1)
    k_gemm<<<N_NODES / 8, 256, 0, stream>>>(x, W1, xw);
    k_aggregate<<<N_NODES / 4, 256, 0, stream>>>(xw, h1, rp, csr_src, csr_w, dinv, b1, 0);

    // layer 2: xw = h1@W2 ; xg = sigmoid(agg + b2)
    k_gemm<<<N_NODES / 8, 256, 0, stream>>>(h1, W2, xw);
    k_aggregate<<<N_NODES / 4, 256, 0, stream>>>(xw, xg, rp, csr_src, csr_w, dinv, b2, 1);

    // gating
    k_gate_ur<<<N_NODES / 4, 256, 0, stream>>>(xg, h, Wu, bu, Wr, br, uu, rr);
    k_gate_c<<<N_NODES / 4, 256, 0, stream>>>(xg, h, rr, uu, Wc, bc, out);
}

// Round 3
// 376.023 us; speedup vs baseline: 3.6446x; 1.3634x over previous
//
#include <hip/hip_runtime.h>
#include <math.h>

#define N_NODES 20000
#define N_EDGES 640000
#define HID 128
#define NPAD 20224

typedef __attribute__((ext_vector_type(8))) short bf16x8;
typedef __attribute__((ext_vector_type(4))) float f32x4;

__device__ inline short f2bf(float f) {
    unsigned u = __builtin_bit_cast(unsigned, f);
    u += 0x7fffu + ((u >> 16) & 1u);      // RNE
    return (short)(u >> 16);
}
__device__ inline float bf2f(short s) {
    unsigned u = ((unsigned)(unsigned short)s) << 16;
    return __builtin_bit_cast(float, u);
}
__device__ inline float2 unpack_bf2(unsigned u) {
    float2 f;
    f.x = __builtin_bit_cast(float, u << 16);
    f.y = __builtin_bit_cast(float, u & 0xffff0000u);
    return f;
}
__device__ inline unsigned pack_bf2(float a, float b) {
    return (unsigned)(unsigned short)f2bf(a) | ((unsigned)(unsigned short)f2bf(b) << 16);
}

// ---------- CSR build ----------
__global__ __launch_bounds__(256) void k_init(float* deg, int* cnt) {
    int i = blockIdx.x * 256 + threadIdx.x;
    if (i < N_NODES) { deg[i] = 1.0f; cnt[i] = 0; }
}

__global__ __launch_bounds__(256) void k_deg_hist(float* deg, int* cnt,
                                                  const int* __restrict__ dst,
                                                  const float* __restrict__ ew) {
    int e = blockIdx.x * 256 + threadIdx.x;
    if (e < N_EDGES) {
        int d = dst[e];
        atomicAdd(&deg[d], ew[e]);
        atomicAdd(&cnt[d], 1);
    }
}

__global__ __launch_bounds__(256) void k_dinv(float* dinv) {
    int i = blockIdx.x * 256 + threadIdx.x;
    if (i < N_NODES) {
        float d = dinv[i];
        dinv[i] = d > 0.f ? rsqrtf(d) : 0.f;
    }
}

// single-pass block scan: 20 elems/thread serial + 1024-wide Hillis-Steele
__global__ __launch_bounds__(1024) void k_scan(const int* __restrict__ cnt,
                                               int* __restrict__ rp, int* __restrict__ cur) {
    __shared__ int smem[1024];
    int tid = threadIdx.x;
    int base = tid * 20;
    int loc[20];
    int run = 0;
#pragma unroll
    for (int j = 0; j < 20; j++) {
        int i = base + j;
        int v = (i < N_NODES) ? cnt[i] : 0;
        loc[j] = run; run += v;
    }
    smem[tid] = run;
    __syncthreads();
    for (int off = 1; off < 1024; off <<= 1) {
        int t = (tid >= off) ? smem[tid - off] : 0;
        __syncthreads();
        smem[tid] += t;
        __syncthreads();
    }
    int excl = smem[tid] - run;
#pragma unroll
    for (int j = 0; j < 20; j++) {
        int i = base + j;
        if (i < N_NODES) { int e = excl + loc[j]; rp[i] = e; cur[i] = e; }
    }
    if (tid == 1023) rp[N_NODES] = smem[1023];
}

__global__ __launch_bounds__(256) void k_fill(const int* __restrict__ src,
                                              const int* __restrict__ dst,
                                              const float* __restrict__ ew,
                                              const float* __restrict__ dinv,
                                              int* cur,
                                              int* __restrict__ csr_src,
                                              float* __restrict__ csr_w) {
    int e = blockIdx.x * 256 + threadIdx.x;
    if (e < N_EDGES) {
        int s = src[e], d = dst[e];
        int slot = atomicAdd(&cur[d], 1);
        csr_src[slot] = s;
        csr_w[slot] = dinv[s] * ew[e] * dinv[d];
    }
}

// ---------- fp32 -> bf16 conversions ----------
__global__ __launch_bounds__(256) void k_cvt2(const float* __restrict__ x, const float* __restrict__ h,
                                              short* __restrict__ xb, short* __restrict__ hb) {
    const int NH4 = (N_NODES * HID) / 4;
    int i = blockIdx.x * 256 + threadIdx.x;   // over 2*NH/4
    const float* s; short* d; int idx;
    if (i < NH4) { s = x; d = xb; idx = i; } else { s = h; d = hb; idx = i - NH4; }
    float4 v = ((const float4*)s)[idx];
    short4 o;
    o.x = f2bf(v.x); o.y = f2bf(v.y); o.z = f2bf(v.z); o.w = f2bf(v.w);
    ((short4*)d)[idx] = o;
}

// transpose + convert the 5 weights: WT[n][k] = bf16(W[k][n])
__global__ __launch_bounds__(256) void k_wcvt(const float* __restrict__ W1, const float* __restrict__ W2,
                                              const float* __restrict__ Wu, const float* __restrict__ Wr,
                                              const float* __restrict__ Wc,
                                              short* WT1, short* WT2, short* WTu, short* WTr, short* WTc) {
    int i = blockIdx.x * 256 + threadIdx.x;   // 0..131071
    if (i < 32768) {
        const float* W = (i < 16384) ? W1 : W2;
        short* T = (i < 16384) ? WT1 : WT2;
        int j = i & 16383;
        int n = j >> 7, k = j & 127;
        T[n * 128 + k] = f2bf(W[k * 128 + n]);
    } else {
        int j = i - 32768;
        const float* W = Wu; short* T = WTu;
        if (j >= 65536)      { W = Wc; T = WTc; j -= 65536; }
        else if (j >= 32768) { W = Wr; T = WTr; j -= 32768; }
        int n = j >> 8, k = j & 255;
        T[n * 256 + k] = f2bf(W[k * 128 + n]);
    }
}

// ---------- MFMA GEMM: Cb[M,128] = Ab[M,128] @ W, W given as WT[128 n][128 k] bf16 ----------
__global__ __launch_bounds__(256) void k_gemm_mfma(const short* __restrict__ Ab,
                                                   const short* __restrict__ WT,
                                                   short* __restrict__ Cb) {
    __shared__ short As[64 * 136];            // +8 pad: kills 16-way bank conflicts
    int tid = threadIdx.x;
    int r0 = blockIdx.x * 64;
#pragma unroll
    for (int i = 0; i < 4; i++) {
        int c = tid + i * 256;                // 1024 chunks of 8 bf16
        int row = c >> 4;
        int col0 = (c & 15) * 8;
        int grow = r0 + row;
        bf16x8 v = {0, 0, 0, 0, 0, 0, 0, 0};
        if (grow < N_NODES) v = *(const bf16x8*)(Ab + (size_t)grow * HID + col0);
        *(bf16x8*)(&As[row * 136 + col0]) = v;
    }
    __syncthreads();
    int wave = tid >> 6, lane = tid & 63;
    int m = lane & 15, quad = lane >> 4;
    int mrow = wave * 16 + m;
    f32x4 acc[8];
#pragma unroll
    for (int i = 0; i < 8; i++) acc[i] = (f32x4){0.f, 0.f, 0.f, 0.f};
#pragma unroll
    for (int ks = 0; ks < 4; ks++) {
        int k0 = ks * 32 + quad * 8;
        bf16x8 a = *(const bf16x8*)(&As[mrow * 136 + k0]);
#pragma unroll
        for (int nb = 0; nb < 8; nb++) {
            int n = nb * 16 + m;
            bf16x8 b = *(const bf16x8*)(WT + n * 128 + k0);
            acc[nb] = __builtin_amdgcn_mfma_f32_16x16x32_bf16(a, b, acc[nb], 0, 0, 0);
        }
    }
    int orow0 = r0 + wave * 16 + quad * 4;
#pragma unroll
    for (int nb = 0; nb < 8; nb++) {
        int col = nb * 16 + m;
#pragma unroll
        for (int rg = 0; rg < 4; rg++) {
            int grow = orow0 + rg;
            if (grow < N_NODES) Cb[(size_t)grow * HID + col] = f2bf(acc[nb][rg]);
        }
    }
}

// ---------- gather aggregation (bf16 in, bf16 out): one wave per dst node ----------
__global__ __launch_bounds__(256) void k_aggregate(const short* __restrict__ xw,
                                                   short* __restrict__ outb,
                                                   const int* __restrict__ rp,
                                                   const int* __restrict__ csr_src,
                                                   const float* __restrict__ csr_w,
                                                   const float* __restrict__ dinv,
                                                   const float* __restrict__ bias,
                                                   int act) {
    int node = blockIdx.x * 4 + (threadIdx.x >> 6);
    int lane = threadIdx.x & 63;
    float dv = dinv[node];
    float2 acc = unpack_bf2(((const unsigned*)(xw + (size_t)node * HID))[lane]);
    acc.x *= dv * dv; acc.y *= dv * dv;
    int j = rp[node], end = rp[node + 1];
    for (; j + 3 < end; j += 4) {
        int s0 = csr_src[j], s1 = csr_src[j + 1], s2 = csr_src[j + 2], s3 = csr_src[j + 3];
        float w0 = csr_w[j], w1 = csr_w[j + 1], w2 = csr_w[j + 2], w3 = csr_w[j + 3];
        float2 v0 = unpack_bf2(((const unsigned*)(xw + (size_t)s0 * HID))[lane]);
        float2 v1 = unpack_bf2(((const unsigned*)(xw + (size_t)s1 * HID))[lane]);
        float2 v2 = unpack_bf2(((const unsigned*)(xw + (size_t)s2 * HID))[lane]);
        float2 v3 = unpack_bf2(((const unsigned*)(xw + (size_t)s3 * HID))[lane]);
        acc.x += v0.x * w0; acc.y += v0.y * w0;
        acc.x += v1.x * w1; acc.y += v1.y * w1;
        acc.x += v2.x * w2; acc.y += v2.y * w2;
        acc.x += v3.x * w3; acc.y += v3.y * w3;
    }
    for (; j < end; j++) {
        int s = csr_src[j];
        float w = csr_w[j];
        float2 v = unpack_bf2(((const unsigned*)(xw + (size_t)s * HID))[lane]);
        acc.x += v.x * w; acc.y += v.y * w;
    }
    float2 b = ((const float2*)bias)[lane];
    acc.x += b.x; acc.y += b.y;
    if (act == 0) {
        acc.x = fmaxf(acc.x, 0.f); acc.y = fmaxf(acc.y, 0.f);
    } else {
        acc.x = 1.f / (1.f + __expf(-acc.x)); acc.y = 1.f / (1.f + __expf(-acc.y));
    }
    ((unsigned*)(outb + (size_t)node * HID))[lane] = pack_bf2(acc.x, acc.y);
}

// ---------- fused gate: u,r = sig([xg,h]W{u,r}+b); c = tanh([xg,r*h]Wc+bc); out = u*h+(1-u)*c ----------
__global__ __launch_bounds__(256, 2) void k_gate(const short* __restrict__ xgb, const short* __restrict__ hb,
                                                 const float* __restrict__ hf,
                                                 const short* __restrict__ WTu, const short* __restrict__ WTr,
                                                 const short* __restrict__ WTc,
                                                 const float* __restrict__ pbu, const float* __restrict__ pbr,
                                                 const float* __restrict__ pbc,
                                                 float* __restrict__ out) {
    __shared__ short Xs[64 * 264];            // [row][0:128]=xg, [128:256]=h (later r*h); +8 pad
    int tid = threadIdx.x;
    int r0 = blockIdx.x * 64;
#pragma unroll
    for (int i = 0; i < 8; i++) {
        int c = tid + i * 256;                // 2048 chunks of 8 bf16
        int row = c >> 5;
        int col0 = (c & 31) * 8;
        int grow = r0 + row;
        bf16x8 v = {0, 0, 0, 0, 0, 0, 0, 0};
        if (grow < N_NODES) {
            if (col0 < 128) v = *(const bf16x8*)(xgb + (size_t)grow * HID + col0);
            else            v = *(const bf16x8*)(hb + (size_t)grow * HID + (col0 - 128));
        }
        *(bf16x8*)(&Xs[row * 264 + col0]) = v;
    }
    __syncthreads();
    int wave = tid >> 6, lane = tid & 63;
    int m = lane & 15, quad = lane >> 4;
    int mrow = wave * 16 + m;
    f32x4 au[8], ar[8];
#pragma unroll
    for (int i = 0; i < 8; i++) { au[i] = (f32x4){0.f, 0.f, 0.f, 0.f}; ar[i] = au[i]; }
#pragma unroll
    for (int ks = 0; ks < 8; ks++) {
        int k0 = ks * 32 + quad * 8;
        bf16x8 a = *(const bf16x8*)(&Xs[mrow * 264 + k0]);
#pragma unroll
        for (int nb = 0; nb < 8; nb++) {
            int n = nb * 16 + m;
            bf16x8 bu_f = *(const bf16x8*)(WTu + n * 256 + k0);
            au[nb] = __builtin_amdgcn_mfma_f32_16x16x32_bf16(a, bu_f, au[nb], 0, 0, 0);
            bf16x8 br_f = *(const bf16x8*)(WTr + n * 256 + k0);
            ar[nb] = __builtin_amdgcn_mfma_f32_16x16x32_bf16(a, br_f, ar[nb], 0, 0, 0);
        }
    }
    // r -> r*h written in place over the h half (rows are wave-local)
    int trow0 = wave * 16 + quad * 4;
#pragma unroll
    for (int nb = 0; nb < 8; nb++) {
        int col = nb * 16 + m;
        float brv = pbr[col];
#pragma unroll
        for (int rg = 0; rg < 4; rg++) {
            int trow = trow0 + rg;
            float rv = 1.f / (1.f + __expf(-(ar[nb][rg] + brv)));
            float hv = bf2f(Xs[trow * 264 + 128 + col]);
            Xs[trow * 264 + 128 + col] = f2bf(rv * hv);
        }
    }
    __syncthreads();
    f32x4 ac[8];
#pragma unroll
    for (int i = 0; i < 8; i++) ac[i] = (f32x4){0.f, 0.f, 0.f, 0.f};
#pragma unroll
    for (int ks = 0; ks < 8; ks++) {
        int k0 = ks * 32 + quad * 8;
        bf16x8 a = *(const bf16x8*)(&Xs[mrow * 264 + k0]);
#pragma unroll
        for (int nb = 0; nb < 8; nb++) {
            int n = nb * 16 + m;
            bf16x8 bc_f = *(const bf16x8*)(WTc + n * 256 + k0);
            ac[nb] = __builtin_amdgcn_mfma_f32_16x16x32_bf16(a, bc_f, ac[nb], 0, 0, 0);
        }
    }
#pragma unroll
    for (int nb = 0; nb < 8; nb++) {
        int col = nb * 16 + m;
        float buv = pbu[col], bcv = pbc[col];
#pragma unroll
        for (int rg = 0; rg < 4; rg++) {
            int grow = r0 + trow0 + rg;
            if (grow < N_NODES) {
                float uv = 1.f / (1.f + __expf(-(au[nb][rg] + buv)));
                float cv = tanhf(ac[nb][rg] + bcv);
                float hv = hf[(size_t)grow * HID + col];
                out[(size_t)grow * HID + col] = uv * hv + (1.f - uv) * cv;
            }
        }
    }
}

extern "C" void kernel_launch(void* const* d_in, const int* in_sizes, int n_in,
                              void* d_out, int out_size, void* d_ws, size_t ws_size,
                              hipStream_t stream) {
    const float* x  = (const float*)d_in[0];
    const int*   ei = (const int*)d_in[1];
    const float* ew = (const float*)d_in[2];
    const float* h  = (const float*)d_in[3];
    const float* W1 = (const float*)d_in[4];
    const float* b1 = (const float*)d_in[5];
    const float* W2 = (const float*)d_in[6];
    const float* b2 = (const float*)d_in[7];
    const float* Wu = (const float*)d_in[8];
    const float* bu = (const float*)d_in[9];
    const float* Wr = (const float*)d_in[10];
    const float* br = (const float*)d_in[11];
    const float* Wc = (const float*)d_in[12];
    const float* bc = (const float*)d_in[13];
    const int* src = ei;
    const int* dst = ei + N_EDGES;
    float* out = (float*)d_out;

    const size_t NH = (size_t)N_NODES * HID;
    float* ws      = (float*)d_ws;
    float* dinv    = ws;
    int*   rp      = (int*)(ws + NPAD);
    int*   cnt     = (int*)(ws + 2 * NPAD);
    int*   cur     = (int*)(ws + 3 * NPAD);
    int*   csr_src = (int*)(ws + 4 * NPAD);
    float* csr_w   = ws + 4 * NPAD + N_EDGES;
    short* xb  = (short*)(ws + 4 * NPAD + 2 * N_EDGES);
    short* hb  = xb + NH;
    short* xw  = hb + NH;          // gemm output, reused both layers
    short* h1b = xw + NH;
    short* xgb = h1b + NH;
    short* WT1 = xgb + NH;
    short* WT2 = WT1 + 16384;
    short* WTu = WT2 + 16384;
    short* WTr = WTu + 32768;
    short* WTc = WTr + 32768;

    // CSR + normalization
    k_init<<<(N_NODES + 255) / 256, 256, 0, stream>>>(dinv, cnt);
    k_deg_hist<<<N_EDGES / 256, 256, 0, stream>>>(dinv, cnt, dst, ew);
    k_dinv<<<(N_NODES + 255) / 256, 256, 0, stream>>>(dinv);
    k_scan<<<1, 1024, 0, stream>>>(cnt, rp, cur);
    k_fill<<<N_EDGES / 256, 256, 0, stream>>>(src, dst, ew, dinv, cur, csr_src, csr_w);

    // bf16 conversions
    k_cvt2<<<(int)(2 * NH / 1024), 256, 0, stream>>>(x, h, xb, hb);
    k_wcvt<<<512, 256, 0, stream>>>(W1, W2, Wu, Wr, Wc, WT1, WT2, WTu, WTr, WTc);

    // layer 1
    k_gemm_mfma<<<(N_NODES + 63) / 64, 256, 0, stream>>>(xb, WT1, xw);
    k_aggregate<<<N_NODES / 4, 256, 0, stream>>>(xw, h1b, rp, csr_src, csr_w, dinv, b1, 0);
    // layer 2
    k_gemm_mfma<<<(N_NODES + 63) / 64, 256, 0, stream>>>(h1b, WT2, xw);
    k_aggregate<<<N_NODES / 4, 256, 0, stream>>>(xw, xgb, rp, csr_src, csr_w, dinv, b2, 1);
    // fused gating
    k_gate<<<(N_NODES + 63) / 64, 256, 0, stream>>>(xgb, hb, h, WTu, WTr, WTc, bu, br, bc, out);
}

// Round 4
// 309.487 us; speedup vs baseline: 4.4281x; 1.2150x over previous
//
#include <hip/hip_runtime.h>
#include <math.h>

#define N_NODES 20000
#define N_EDGES 640000
#define HID 128
#define NPAD 20224

typedef __attribute__((ext_vector_type(8))) short bf16x8;
typedef __attribute__((ext_vector_type(4))) float f32x4;

#define FIX_SCALE 274877906944.0   // 2^38
#define FIX_MASK ((1ull << 48) - 1)

__device__ inline short f2bf(float f) {
    unsigned u = __builtin_bit_cast(unsigned, f);
    u += 0x7fffu + ((u >> 16) & 1u);      // RNE
    return (short)(u >> 16);
}
__device__ inline float bf2f(short s) {
    unsigned u = ((unsigned)(unsigned short)s) << 16;
    return __builtin_bit_cast(float, u);
}
__device__ inline float4 unpack_bf4(uint2 v) {
    float4 f;
    f.x = __builtin_bit_cast(float, v.x << 16);
    f.y = __builtin_bit_cast(float, v.x & 0xffff0000u);
    f.z = __builtin_bit_cast(float, v.y << 16);
    f.w = __builtin_bit_cast(float, v.y & 0xffff0000u);
    return f;
}
__device__ inline uint2 pack_bf4(float4 f) {
    uint2 v;
    v.x = (unsigned)(unsigned short)f2bf(f.x) | ((unsigned)(unsigned short)f2bf(f.y) << 16);
    v.y = (unsigned)(unsigned short)f2bf(f.z) | ((unsigned)(unsigned short)f2bf(f.w) << 16);
    return v;
}

// ---------- CSR build ----------
__global__ __launch_bounds__(256) void k_init(unsigned long long* packed) {
    int i = blockIdx.x * 256 + threadIdx.x;
    if (i < N_NODES) packed[i] = 0ull;
}

// one u64 atomic per edge: count in [63:48], fixed-point weighted degree in [47:0];
// returned old count = this edge's rank within its dst bucket
__global__ __launch_bounds__(256) void k_hist(unsigned long long* packed, int* __restrict__ rank,
                                              const int* __restrict__ dst,
                                              const float* __restrict__ ew) {
    int e = blockIdx.x * 256 + threadIdx.x;
    if (e < N_EDGES) {
        int d = dst[e];
        unsigned long long add = (1ull << 48) | (unsigned long long)((double)ew[e] * FIX_SCALE);
        unsigned long long old = atomicAdd(&packed[d], add);
        rank[e] = (int)(old >> 48);
    }
}

__global__ __launch_bounds__(256) void k_dinv(const unsigned long long* __restrict__ packed,
                                              float* __restrict__ dinv) {
    int i = blockIdx.x * 256 + threadIdx.x;
    if (i < N_NODES) {
        double deg = 1.0 + (double)(packed[i] & FIX_MASK) * (1.0 / FIX_SCALE);  // +1 self-loop
        dinv[i] = rsqrtf((float)deg);
    }
}

// single-pass block scan of counts -> row_ptr
__global__ __launch_bounds__(1024) void k_scan(const unsigned long long* __restrict__ packed,
                                               int* __restrict__ rp) {
    __shared__ int smem[1024];
    int tid = threadIdx.x;
    int base = tid * 20;
    int loc[20];
    int run = 0;
#pragma unroll
    for (int j = 0; j < 20; j++) {
        int i = base + j;
        int v = (i < N_NODES) ? (int)(packed[i] >> 48) : 0;
        loc[j] = run; run += v;
    }
    smem[tid] = run;
    __syncthreads();
    for (int off = 1; off < 1024; off <<= 1) {
        int t = (tid >= off) ? smem[tid - off] : 0;
        __syncthreads();
        smem[tid] += t;
        __syncthreads();
    }
    int excl = smem[tid] - run;
#pragma unroll
    for (int j = 0; j < 20; j++) {
        int i = base + j;
        if (i < N_NODES) rp[i] = excl + loc[j];
    }
    if (tid == 1023) rp[N_NODES] = smem[1023];
}

// atomic-free fill: slot = rp[dst] + rank; one 8B scattered store per edge
__global__ __launch_bounds__(256) void k_fill(const int* __restrict__ src,
                                              const int* __restrict__ dst,
                                              const float* __restrict__ ew,
                                              const float* __restrict__ dinv,
                                              const int* __restrict__ rp,
                                              const int* __restrict__ rank,
                                              int2* __restrict__ csr) {
    int e = blockIdx.x * 256 + threadIdx.x;
    if (e < N_EDGES) {
        int s = src[e], d = dst[e];
        int slot = rp[d] + rank[e];
        float w = dinv[s] * ew[e] * dinv[d];
        csr[slot] = make_int2(s, __builtin_bit_cast(int, w));
    }
}

// ---------- fp32 -> bf16 conversions ----------
__global__ __launch_bounds__(256) void k_cvt2(const float* __restrict__ x, const float* __restrict__ h,
                                              short* __restrict__ xb, short* __restrict__ hb) {
    const int NH4 = (N_NODES * HID) / 4;
    int i = blockIdx.x * 256 + threadIdx.x;
    const float* s; short* d; int idx;
    if (i < NH4) { s = x; d = xb; idx = i; } else { s = h; d = hb; idx = i - NH4; }
    float4 v = ((const float4*)s)[idx];
    short4 o;
    o.x = f2bf(v.x); o.y = f2bf(v.y); o.z = f2bf(v.z); o.w = f2bf(v.w);
    ((short4*)d)[idx] = o;
}

// transpose + convert the 5 weights: WT[n][k] = bf16(W[k][n])
__global__ __launch_bounds__(256) void k_wcvt(const float* __restrict__ W1, const float* __restrict__ W2,
                                              const float* __restrict__ Wu, const float* __restrict__ Wr,
                                              const float* __restrict__ Wc,
                                              short* WT1, short* WT2, short* WTu, short* WTr, short* WTc) {
    int i = blockIdx.x * 256 + threadIdx.x;   // 0..131071
    if (i < 32768) {
        const float* W = (i < 16384) ? W1 : W2;
        short* T = (i < 16384) ? WT1 : WT2;
        int j = i & 16383;
        int n = j >> 7, k = j & 127;
        T[n * 128 + k] = f2bf(W[k * 128 + n]);
    } else {
        int j = i - 32768;
        const float* W = Wu; short* T = WTu;
        if (j >= 65536)      { W = Wc; T = WTc; j -= 65536; }
        else if (j >= 32768) { W = Wr; T = WTr; j -= 32768; }
        int n = j >> 8, k = j & 255;
        T[n * 256 + k] = f2bf(W[k * 128 + n]);
    }
}

// ---------- MFMA GEMM: Cb[M,128] = Ab[M,128] @ W, W given as WT[128 n][128 k] bf16 ----------
__global__ __launch_bounds__(256) void k_gemm_mfma(const short* __restrict__ Ab,
                                                   const short* __restrict__ WT,
                                                   short* __restrict__ Cb) {
    __shared__ short As[64 * 136];
    int tid = threadIdx.x;
    int r0 = blockIdx.x * 64;
#pragma unroll
    for (int i = 0; i < 4; i++) {
        int c = tid + i * 256;
        int row = c >> 4;
        int col0 = (c & 15) * 8;
        int grow = r0 + row;
        bf16x8 v = {0, 0, 0, 0, 0, 0, 0, 0};
        if (grow < N_NODES) v = *(const bf16x8*)(Ab + (size_t)grow * HID + col0);
        *(bf16x8*)(&As[row * 136 + col0]) = v;
    }
    __syncthreads();
    int wave = tid >> 6, lane = tid & 63;
    int m = lane & 15, quad = lane >> 4;
    int mrow = wave * 16 + m;
    f32x4 acc[8];
#pragma unroll
    for (int i = 0; i < 8; i++) acc[i] = (f32x4){0.f, 0.f, 0.f, 0.f};
#pragma unroll
    for (int ks = 0; ks < 4; ks++) {
        int k0 = ks * 32 + quad * 8;
        bf16x8 a = *(const bf16x8*)(&As[mrow * 136 + k0]);
#pragma unroll
        for (int nb = 0; nb < 8; nb++) {
            int n = nb * 16 + m;
            bf16x8 b = *(const bf16x8*)(WT + n * 128 + k0);
            acc[nb] = __builtin_amdgcn_mfma_f32_16x16x32_bf16(a, b, acc[nb], 0, 0, 0);
        }
    }
    int orow0 = r0 + wave * 16 + quad * 4;
#pragma unroll
    for (int nb = 0; nb < 8; nb++) {
        int col = nb * 16 + m;
#pragma unroll
        for (int rg = 0; rg < 4; rg++) {
            int grow = orow0 + rg;
            if (grow < N_NODES) Cb[(size_t)grow * HID + col] = f2bf(acc[nb][rg]);
        }
    }
}

// ---------- gather aggregation: one wave per dst node, half-wave per row ----------
// lane = half*32 + l; lane covers cols l*4..l*4+3 (uint2 = 4 bf16); halves split edges, shfl-combined
__global__ __launch_bounds__(256) void k_aggregate(const short* __restrict__ xw,
                                                   short* __restrict__ outb,
                                                   const int* __restrict__ rp,
                                                   const int2* __restrict__ csr,
                                                   const float* __restrict__ dinv,
                                                   const float* __restrict__ bias,
                                                   int act) {
    int node = blockIdx.x * 4 + (threadIdx.x >> 6);
    int lane = threadIdx.x & 63;
    int half = lane >> 5;
    int l = lane & 31;
    float4 acc = {0.f, 0.f, 0.f, 0.f};
    if (half == 0) {   // self-loop term, counted once
        float dv = dinv[node];
        float dv2 = dv * dv;
        float4 v = unpack_bf4(((const uint2*)(xw + (size_t)node * HID))[l]);
        acc.x = v.x * dv2; acc.y = v.y * dv2; acc.z = v.z * dv2; acc.w = v.w * dv2;
    }
    int j = rp[node], end = rp[node + 1];
    for (; j + 7 < end; j += 8) {
        int2 e0 = csr[j + 0 + half];
        int2 e1 = csr[j + 2 + half];
        int2 e2 = csr[j + 4 + half];
        int2 e3 = csr[j + 6 + half];
        float4 v0 = unpack_bf4(((const uint2*)(xw + (size_t)e0.x * HID))[l]);
        float4 v1 = unpack_bf4(((const uint2*)(xw + (size_t)e1.x * HID))[l]);
        float4 v2 = unpack_bf4(((const uint2*)(xw + (size_t)e2.x * HID))[l]);
        float4 v3 = unpack_bf4(((const uint2*)(xw + (size_t)e3.x * HID))[l]);
        float w0 = __builtin_bit_cast(float, e0.y);
        float w1 = __builtin_bit_cast(float, e1.y);
        float w2 = __builtin_bit_cast(float, e2.y);
        float w3 = __builtin_bit_cast(float, e3.y);
        acc.x += v0.x * w0; acc.y += v0.y * w0; acc.z += v0.z * w0; acc.w += v0.w * w0;
        acc.x += v1.x * w1; acc.y += v1.y * w1; acc.z += v1.z * w1; acc.w += v1.w * w1;
        acc.x += v2.x * w2; acc.y += v2.y * w2; acc.z += v2.z * w2; acc.w += v2.w * w2;
        acc.x += v3.x * w3; acc.y += v3.y * w3; acc.z += v3.z * w3; acc.w += v3.w * w3;
    }
    for (; j + 1 < end; j += 2) {
        int2 e0 = csr[j + half];
        float4 v0 = unpack_bf4(((const uint2*)(xw + (size_t)e0.x * HID))[l]);
        float w0 = __builtin_bit_cast(float, e0.y);
        acc.x += v0.x * w0; acc.y += v0.y * w0; acc.z += v0.z * w0; acc.w += v0.w * w0;
    }
    if (j < end && half == 0) {   // odd tail edge
        int2 e0 = csr[j];
        float4 v0 = unpack_bf4(((const uint2*)(xw + (size_t)e0.x * HID))[l]);
        float w0 = __builtin_bit_cast(float, e0.y);
        acc.x += v0.x * w0; acc.y += v0.y * w0; acc.z += v0.z * w0; acc.w += v0.w * w0;
    }
    // combine halves (same cols, disjoint edge subsets)
    acc.x += __shfl_xor(acc.x, 32);
    acc.y += __shfl_xor(acc.y, 32);
    acc.z += __shfl_xor(acc.z, 32);
    acc.w += __shfl_xor(acc.w, 32);
    if (half == 0) {
        float4 b = ((const float4*)bias)[l];
        acc.x += b.x; acc.y += b.y; acc.z += b.z; acc.w += b.w;
        if (act == 0) {
            acc.x = fmaxf(acc.x, 0.f); acc.y = fmaxf(acc.y, 0.f);
            acc.z = fmaxf(acc.z, 0.f); acc.w = fmaxf(acc.w, 0.f);
        } else {
            acc.x = 1.f / (1.f + __expf(-acc.x)); acc.y = 1.f / (1.f + __expf(-acc.y));
            acc.z = 1.f / (1.f + __expf(-acc.z)); acc.w = 1.f / (1.f + __expf(-acc.w));
        }
        ((uint2*)(outb + (size_t)node * HID))[l] = pack_bf4(acc);
    }
}

// ---------- fused gate ----------
__global__ __launch_bounds__(256, 2) void k_gate(const short* __restrict__ xgb, const short* __restrict__ hb,
                                                 const float* __restrict__ hf,
                                                 const short* __restrict__ WTu, const short* __restrict__ WTr,
                                                 const short* __restrict__ WTc,
                                                 const float* __restrict__ pbu, const float* __restrict__ pbr,
                                                 const float* __restrict__ pbc,
                                                 float* __restrict__ out) {
    __shared__ short Xs[64 * 264];
    int tid = threadIdx.x;
    int r0 = blockIdx.x * 64;
#pragma unroll
    for (int i = 0; i < 8; i++) {
        int c = tid + i * 256;
        int row = c >> 5;
        int col0 = (c & 31) * 8;
        int grow = r0 + row;
        bf16x8 v = {0, 0, 0, 0, 0, 0, 0, 0};
        if (grow < N_NODES) {
            if (col0 < 128) v = *(const bf16x8*)(xgb + (size_t)grow * HID + col0);
            else            v = *(const bf16x8*)(hb + (size_t)grow * HID + (col0 - 128));
        }
        *(bf16x8*)(&Xs[row * 264 + col0]) = v;
    }
    __syncthreads();
    int wave = tid >> 6, lane = tid & 63;
    int m = lane & 15, quad = lane >> 4;
    int mrow = wave * 16 + m;
    f32x4 au[8], ar[8];
#pragma unroll
    for (int i = 0; i < 8; i++) { au[i] = (f32x4){0.f, 0.f, 0.f, 0.f}; ar[i] = au[i]; }
#pragma unroll
    for (int ks = 0; ks < 8; ks++) {
        int k0 = ks * 32 + quad * 8;
        bf16x8 a = *(const bf16x8*)(&Xs[mrow * 264 + k0]);
#pragma unroll
        for (int nb = 0; nb < 8; nb++) {
            int n = nb * 16 + m;
            bf16x8 bu_f = *(const bf16x8*)(WTu + n * 256 + k0);
            au[nb] = __builtin_amdgcn_mfma_f32_16x16x32_bf16(a, bu_f, au[nb], 0, 0, 0);
            bf16x8 br_f = *(const bf16x8*)(WTr + n * 256 + k0);
            ar[nb] = __builtin_amdgcn_mfma_f32_16x16x32_bf16(a, br_f, ar[nb], 0, 0, 0);
        }
    }
    int trow0 = wave * 16 + quad * 4;
#pragma unroll
    for (int nb = 0; nb < 8; nb++) {
        int col = nb * 16 + m;
        float brv = pbr[col];
#pragma unroll
        for (int rg = 0; rg < 4; rg++) {
            int trow = trow0 + rg;
            float rv = 1.f / (1.f + __expf(-(ar[nb][rg] + brv)));
            float hv = bf2f(Xs[trow * 264 + 128 + col]);
            Xs[trow * 264 + 128 + col] = f2bf(rv * hv);
        }
    }
    __syncthreads();
    f32x4 ac[8];
#pragma unroll
    for (int i = 0; i < 8; i++) ac[i] = (f32x4){0.f, 0.f, 0.f, 0.f};
#pragma unroll
    for (int ks = 0; ks < 8; ks++) {
        int k0 = ks * 32 + quad * 8;
        bf16x8 a = *(const bf16x8*)(&Xs[mrow * 264 + k0]);
#pragma unroll
        for (int nb = 0; nb < 8; nb++) {
            int n = nb * 16 + m;
            bf16x8 bc_f = *(const bf16x8*)(WTc + n * 256 + k0);
            ac[nb] = __builtin_amdgcn_mfma_f32_16x16x32_bf16(a, bc_f, ac[nb], 0, 0, 0);
        }
    }
#pragma unroll
    for (int nb = 0; nb < 8; nb++) {
        int col = nb * 16 + m;
        float buv = pbu[col], bcv = pbc[col];
#pragma unroll
        for (int rg = 0; rg < 4; rg++) {
            int grow = r0 + trow0 + rg;
            if (grow < N_NODES) {
                float uv = 1.f / (1.f + __expf(-(au[nb][rg] + buv)));
                float cv = tanhf(ac[nb][rg] + bcv);
                float hv = hf[(size_t)grow * HID + col];
                out[(size_t)grow * HID + col] = uv * hv + (1.f - uv) * cv;
            }
        }
    }
}

extern "C" void kernel_launch(void* const* d_in, const int* in_sizes, int n_in,
                              void* d_out, int out_size, void* d_ws, size_t ws_size,
                              hipStream_t stream) {
    const float* x  = (const float*)d_in[0];
    const int*   ei = (const int*)d_in[1];
    const float* ew = (const float*)d_in[2];
    const float* h  = (const float*)d_in[3];
    const float* W1 = (const float*)d_in[4];
    const float* b1 = (const float*)d_in[5];
    const float* W2 = (const float*)d_in[6];
    const float* b2 = (const float*)d_in[7];
    const float* Wu = (const float*)d_in[8];
    const float* bu = (const float*)d_in[9];
    const float* Wr = (const float*)d_in[10];
    const float* br = (const float*)d_in[11];
    const float* Wc = (const float*)d_in[12];
    const float* bc = (const float*)d_in[13];
    const int* src = ei;
    const int* dst = ei + N_EDGES;
    float* out = (float*)d_out;

    const size_t NH = (size_t)N_NODES * HID;
    float* ws = (float*)d_ws;
    float* dinv = ws;                                          // NPAD
    int*   rp   = (int*)(ws + NPAD);                           // NPAD
    unsigned long long* packed = (unsigned long long*)(ws + 2 * NPAD);  // NPAD u64 (= 2*NPAD f32)
    int*   rank = (int*)(ws + 4 * NPAD);                       // N_EDGES
    int2*  csr  = (int2*)(ws + 4 * NPAD + N_EDGES);            // N_EDGES int2
    short* xb  = (short*)(ws + 4 * NPAD + 3 * N_EDGES);
    short* hb  = xb + NH;
    short* xw  = hb + NH;
    short* h1b = xw + NH;
    short* xgb = h1b + NH;
    short* WT1 = xgb + NH;
    short* WT2 = WT1 + 16384;
    short* WTu = WT2 + 16384;
    short* WTr = WTu + 32768;
    short* WTc = WTr + 32768;

    // CSR + normalization (1 atomic per edge total)
    k_init<<<(N_NODES + 255) / 256, 256, 0, stream>>>(packed);
    k_hist<<<N_EDGES / 256, 256, 0, stream>>>(packed, rank, dst, ew);
    k_dinv<<<(N_NODES + 255) / 256, 256, 0, stream>>>(packed, dinv);
    k_scan<<<1, 1024, 0, stream>>>(packed, rp);
    k_fill<<<N_EDGES / 256, 256, 0, stream>>>(src, dst, ew, dinv, rp, rank, csr);

    // bf16 conversions
    k_cvt2<<<(int)(2 * NH / 1024), 256, 0, stream>>>(x, h, xb, hb);
    k_wcvt<<<512, 256, 0, stream>>>(W1, W2, Wu, Wr, Wc, WT1, WT2, WTu, WTr, WTc);

    // layer 1
    k_gemm_mfma<<<(N_NODES + 63) / 64, 256, 0, stream>>>(xb, WT1, xw);
    k_aggregate<<<N_NODES / 4, 256, 0, stream>>>(xw, h1b, rp, csr, dinv, b1, 0);
    // layer 2
    k_gemm_mfma<<<(N_NODES + 63) / 64, 256, 0, stream>>>(h1b, WT2, xw);
    k_aggregate<<<N_NODES / 4, 256, 0, stream>>>(xw, xgb, rp, csr, dinv, b2, 1);
    // fused gating
    k_gate<<<(N_NODES + 63) / 64, 256, 0, stream>>>(xgb, hb, h, WTu, WTr, WTc, bu, br, bc, out);
}